// Round 1
// baseline (2463.345 us; speedup 1.0000x reference)
//
#include <hip/hip_runtime.h>
#include <stdint.h>

// ---------------------------------------------------------------------------
// OneScaleMultiStepPredictor — MFMA bf16 implementation.
//
// Pipeline (C=64 everywhere):
//   h  = prelu(requant([rec_F | bins1]) @ dec_W + dec_b, dec_a)          [N,64]
//   r1 = requant(prelu(conv27(rec, requant(h), W1) + b1, a1))            [N,64]
//   r2 = conv27(rec, r1, W2) + b2 ; rec_out = h + r2  -> d_out[0:N*64]
//   pq = requant(rec_out)
//   qq = requant(prelu(conv27(rec, pq, p0_Wc) + p0_bc, p0_ac))
//   tq = requant( qq[parent(m)] @ p0_Wl[:, bit(m)*64 : +64] )            [M,64]
//   uq = requant(prelu(conv27(child, tq, p1_Wc) + p1_bc, p1_ac))
//   pred = uq @ p1_Wl  -> d_out[N*64 : +M*255]
//   oct  = sum(bins0<<k)-1 -> d_out[N*64+M*255 : +M]
//
// MFMA k-mapping note: A and B fragments are BOTH packed with k^(g,e)=g*8+e
// (g = lane>>4, e = elem). The HW contracts matching (g,e) slots of A and B,
// so any shared bijection gives the correct dot product independent of the
// true per-instruction K ordering. C/D layout per learn_hip m89:
// col = lane&15, row = (lane>>4)*4 + reg.
// ---------------------------------------------------------------------------

typedef short bf16x8 __attribute__((ext_vector_type(8)));
typedef float f32x4 __attribute__((ext_vector_type(4)));

#define EMPTY_KEY 0xFFFFFFFFu

__device__ __forceinline__ float rq(float x) {
  x *= (1.0f / 256.0f);
  return fminf(fmaxf(x, -128.0f), 127.0f);
}

__device__ __forceinline__ short f2b(float f) {  // fp32 -> bf16 (RNE)
  union { float f; uint32_t u; } v; v.f = f;
  uint32_t u = v.u;
  uint32_t r = (u + 0x7FFFu + ((u >> 16) & 1u)) >> 16;
  return (short)r;
}

__device__ __forceinline__ uint32_t hkey(int x, int y, int z) {
  // coords in [-2, 512]; +8 -> [6,520] < 1024 -> injective 30-bit key
  return ((uint32_t)(x + 8) << 20) | ((uint32_t)(y + 8) << 10) | (uint32_t)(z + 8);
}
__device__ __forceinline__ uint32_t hfun(uint32_t key, uint32_t mask) {
  return (key * 2654435761u) & mask;
}

// ------------------------------ setup kernels ------------------------------

__global__ void k_fill_u32(uint32_t* p, int n, uint32_t v) {
  int i = blockIdx.x * 256 + threadIdx.x;
  if (i < n) p[i] = v;
}

__global__ void k_hash_insert(const int* __restrict__ coords, int n,
                              uint32_t* __restrict__ keys, int* __restrict__ vals,
                              uint32_t mask) {
  int i = blockIdx.x * 256 + threadIdx.x;
  if (i >= n) return;
  uint32_t key = hkey(coords[i * 3], coords[i * 3 + 1], coords[i * 3 + 2]);
  uint32_t s = hfun(key, mask);
  while (true) {
    uint32_t old = atomicCAS(&keys[s], EMPTY_KEY, key);
    if (old == EMPTY_KEY) { vals[s] = i; return; }   // coords are unique
    s = (s + 1) & mask;
  }
}

__global__ void k_build_nbr(const int* __restrict__ coords, int n, int stride,
                            const uint32_t* __restrict__ keys,
                            const int* __restrict__ vals, uint32_t mask,
                            int* __restrict__ nbr) {
  int t = blockIdx.x * 256 + threadIdx.x;
  if (t >= n * 27) return;
  int i = t / 27, k = t % 27;
  int dx = k / 9 - 1, dy = (k / 3) % 3 - 1, dz = k % 3 - 1;
  int x = coords[i * 3] + dx * stride;
  int y = coords[i * 3 + 1] + dy * stride;
  int z = coords[i * 3 + 2] + dz * stride;
  uint32_t key = hkey(x, y, z);
  uint32_t s = hfun(key, mask);
  int res = -1;
  while (true) {
    uint32_t kk = keys[s];
    if (kk == key) { res = vals[s]; break; }
    if (kk == EMPTY_KEY) break;
    s = (s + 1) & mask;
  }
  nbr[t] = res;
}

// Pack conv weight W[27][64][64] (fp32) -> [k][t][c][lane][8] bf16 fragments.
__global__ void k_pack_conv(const float* __restrict__ W, short* __restrict__ dst) {
  int gid = blockIdx.x * 256 + threadIdx.x;
  if (gid >= 27 * 2 * 4 * 64) return;
  int lane = gid & 63;
  int c = (gid >> 6) & 3;
  int t = (gid >> 8) & 1;
  int k = gid >> 9;
  int n = c * 16 + (lane & 15);
  int g = lane >> 4;
  bf16x8 v;
#pragma unroll
  for (int e = 0; e < 8; e++) {
    int kk = t * 32 + g * 8 + e;
    v[e] = f2b(W[(k * 64 + kk) * 64 + n]);
  }
  *(bf16x8*)(dst + gid * 8) = v;
}

// Pack dense weight [K][Ncols] fp32 -> [t][c][lane][8] bf16 (zero-padded).
__global__ void k_pack_dense(const float* __restrict__ W, short* __restrict__ dst,
                             int K, int Ncols, int KT, int CT) {
  int gid = blockIdx.x * 256 + threadIdx.x;
  if (gid >= KT * CT * 64) return;
  int lane = gid & 63;
  int c = (gid >> 6) % CT;
  int t = gid / (64 * CT);
  int n = c * 16 + (lane & 15);
  int g = lane >> 4;
  bf16x8 v;
#pragma unroll
  for (int e = 0; e < 8; e++) {
    int kk = t * 32 + g * 8 + e;
    float val = (kk < K && n < Ncols) ? W[kk * Ncols + n] : 0.0f;
    v[e] = f2b(val);
  }
  *(bf16x8*)(dst + gid * 8) = v;
}

__global__ void k_bucket(const int* __restrict__ child_idx, int M,
                         int* __restrict__ lists, int* __restrict__ cnt) {
  int m = blockIdx.x * 256 + threadIdx.x;
  if (m >= M) return;
  int b = child_idx[m] & 7;
  int pos = atomicAdd(&cnt[b], 1);
  lists[b * M + pos] = m;
}

// ------------------------------ compute kernels ----------------------------

// dec: h = prelu(requant([rec_F | bins1]) @ dec_W + b, a); h32 + requant bf16
__global__ void __launch_bounds__(256)
k_dec(const float* __restrict__ recF, const int* __restrict__ bits,
      const short* __restrict__ wp, const float* __restrict__ bias,
      const float* __restrict__ alpha, float* __restrict__ h32,
      short* __restrict__ hq) {
  int tid = threadIdx.x, wid = tid >> 6, lane = tid & 63;
  int rowbase = blockIdx.x * 64 + wid * 16;
  int lrow = rowbase + (lane & 15);
  int g = lane >> 4;
  f32x4 acc[4] = {};
#pragma unroll
  for (int t = 0; t < 3; t++) {
    bf16x8 a = {0, 0, 0, 0, 0, 0, 0, 0};
    if (t < 2) {
      const float* src = recF + (size_t)lrow * 64 + t * 32 + g * 8;
#pragma unroll
      for (int e = 0; e < 8; e++) a[e] = f2b(rq(src[e]));
    } else if (g == 0) {
      const int* bp = bits + (size_t)lrow * 8;
#pragma unroll
      for (int e = 0; e < 8; e++) a[e] = f2b((float)bp[e]);  // requant(bit*256)=bit
    }
#pragma unroll
    for (int c = 0; c < 4; c++) {
      bf16x8 b = *(const bf16x8*)(wp + ((t * 4 + c) * 64 + lane) * 8);
      acc[c] = __builtin_amdgcn_mfma_f32_16x16x32_bf16(a, b, acc[c], 0, 0, 0);
    }
  }
#pragma unroll
  for (int c = 0; c < 4; c++) {
    int col = c * 16 + (lane & 15);
    float bi = bias[col], al = alpha[col];
#pragma unroll
    for (int r = 0; r < 4; r++) {
      int row = rowbase + g * 4 + r;
      float v = acc[c][r] + bi;
      v = v >= 0.0f ? v : al * v;
      h32[(size_t)row * 64 + col] = v;
      hq[(size_t)row * 64 + col] = f2b(rq(v));
    }
  }
}

// 27-point gather conv. MODE 0: outq = requant(prelu(acc+b, a)).
// MODE 1: out32 = resid + acc + b (written to d_out); outq = requant(out32).
template <int MODE>
__global__ void __launch_bounds__(256)
k_conv(const short* __restrict__ fin, const int* __restrict__ nbr,
       const short* __restrict__ wp, const float* __restrict__ bias,
       const float* __restrict__ alpha, const float* __restrict__ resid,
       float* __restrict__ out32, short* __restrict__ outq) {
  int tid = threadIdx.x, wid = tid >> 6, lane = tid & 63;
  int rowbase = blockIdx.x * 64 + wid * 16;
  int lrow = rowbase + (lane & 15);
  int g = lane >> 4;
  f32x4 acc[4] = {};
  for (int k = 0; k < 27; k++) {
    int nb = nbr[(size_t)lrow * 27 + k];
    bf16x8 a0 = {0, 0, 0, 0, 0, 0, 0, 0};
    bf16x8 a1 = {0, 0, 0, 0, 0, 0, 0, 0};
    if (nb >= 0) {
      const short* fp = fin + (size_t)nb * 64 + g * 8;
      a0 = *(const bf16x8*)fp;
      a1 = *(const bf16x8*)(fp + 32);
    }
    const short* wk = wp + k * 4096;
#pragma unroll
    for (int c = 0; c < 4; c++) {
      bf16x8 b0 = *(const bf16x8*)(wk + (c * 64 + lane) * 8);
      acc[c] = __builtin_amdgcn_mfma_f32_16x16x32_bf16(a0, b0, acc[c], 0, 0, 0);
    }
#pragma unroll
    for (int c = 0; c < 4; c++) {
      bf16x8 b1 = *(const bf16x8*)(wk + ((4 + c) * 64 + lane) * 8);
      acc[c] = __builtin_amdgcn_mfma_f32_16x16x32_bf16(a1, b1, acc[c], 0, 0, 0);
    }
  }
#pragma unroll
  for (int c = 0; c < 4; c++) {
    int col = c * 16 + (lane & 15);
    float bi = bias[col];
    float al = (MODE == 0) ? alpha[col] : 0.0f;
#pragma unroll
    for (int r = 0; r < 4; r++) {
      int row = rowbase + g * 4 + r;
      float v = acc[c][r] + bi;
      if (MODE == 0) {
        v = v >= 0.0f ? v : al * v;
        outq[(size_t)row * 64 + col] = f2b(rq(v));
      } else {
        v += resid[(size_t)row * 64 + col];
        out32[(size_t)row * 64 + col] = v;
        outq[(size_t)row * 64 + col] = f2b(rq(v));
      }
    }
  }
}

// Bucketed p0_Wl projection: tq[m] = requant(qq[parent(m)] @ p0_Wl[:, bit*64:+64])
__global__ void __launch_bounds__(256)
k_p0(const short* __restrict__ qq, const int* __restrict__ child_idx,
     const int* __restrict__ lists, const int* __restrict__ cnt,
     const short* __restrict__ wp, short* __restrict__ tq, int M) {
  int b = blockIdx.y;
  int cb = cnt[b];
  int start = blockIdx.x * 64;
  if (start >= cb) return;
  int tid = threadIdx.x, wid = tid >> 6, lane = tid & 63, g = lane >> 4;
  int posA = start + wid * 16 + (lane & 15);
  int parent = -1;
  if (posA < cb) parent = child_idx[lists[(size_t)b * M + posA]] >> 3;
  f32x4 acc[4] = {};
#pragma unroll
  for (int t = 0; t < 2; t++) {
    bf16x8 a = {0, 0, 0, 0, 0, 0, 0, 0};
    if (parent >= 0) a = *(const bf16x8*)(qq + (size_t)parent * 64 + t * 32 + g * 8);
#pragma unroll
    for (int c = 0; c < 4; c++) {
      bf16x8 bb = *(const bf16x8*)(wp + (((size_t)t * 32 + b * 4 + c) * 64 + lane) * 8);
      acc[c] = __builtin_amdgcn_mfma_f32_16x16x32_bf16(a, bb, acc[c], 0, 0, 0);
    }
  }
#pragma unroll
  for (int r = 0; r < 4; r++) {
    int posD = start + wid * 16 + g * 4 + r;
    if (posD < cb) {
      int m = lists[(size_t)b * M + posD];
#pragma unroll
      for (int c = 0; c < 4; c++) {
        int col = c * 16 + (lane & 15);
        tq[(size_t)m * 64 + col] = f2b(rq(acc[c][r]));
      }
    }
  }
}

// pred = uq @ p1_Wl  (255 cols, padded to 256)
__global__ void __launch_bounds__(256)
k_p1(const short* __restrict__ uq, const short* __restrict__ wp,
     float* __restrict__ out) {
  int tid = threadIdx.x, wid = tid >> 6, lane = tid & 63, g = lane >> 4;
  int rowbase = blockIdx.x * 64 + wid * 16;
  int lrow = rowbase + (lane & 15);
  f32x4 acc[16] = {};
#pragma unroll
  for (int t = 0; t < 2; t++) {
    bf16x8 a = *(const bf16x8*)(uq + (size_t)lrow * 64 + t * 32 + g * 8);
#pragma unroll
    for (int c = 0; c < 16; c++) {
      bf16x8 bb = *(const bf16x8*)(wp + ((t * 16 + c) * 64 + lane) * 8);
      acc[c] = __builtin_amdgcn_mfma_f32_16x16x32_bf16(a, bb, acc[c], 0, 0, 0);
    }
  }
#pragma unroll
  for (int c = 0; c < 16; c++) {
    int col = c * 16 + (lane & 15);
    if (col < 255) {
#pragma unroll
      for (int r = 0; r < 4; r++) {
        int row = rowbase + g * 4 + r;
        out[(size_t)row * 255 + col] = acc[c][r];
      }
    }
  }
}

__global__ void k_oct(const int* __restrict__ bins0, float* __restrict__ out, int M) {
  int m = blockIdx.x * 256 + threadIdx.x;
  if (m >= M) return;
  int s = 0;
#pragma unroll
  for (int e = 0; e < 8; e++) s += bins0[(size_t)m * 8 + e] << e;
  out[m] = (float)(s - 1);
}

// ------------------------------ host launcher ------------------------------

extern "C" void kernel_launch(void* const* d_in, const int* in_sizes, int n_in,
                              void* d_out, int out_size, void* d_ws, size_t ws_size,
                              hipStream_t stream) {
  const float* rec_F  = (const float*)d_in[0];
  const float* dec_W  = (const float*)d_in[1];
  const float* dec_b  = (const float*)d_in[2];
  const float* dec_a  = (const float*)d_in[3];
  const float* res_W1 = (const float*)d_in[4];
  const float* res_b1 = (const float*)d_in[5];
  const float* res_a1 = (const float*)d_in[6];
  const float* res_W2 = (const float*)d_in[7];
  const float* res_b2 = (const float*)d_in[8];
  const float* p0_Wc  = (const float*)d_in[9];
  const float* p0_bc  = (const float*)d_in[10];
  const float* p0_ac  = (const float*)d_in[11];
  const float* p0_Wl  = (const float*)d_in[12];
  const float* p1_Wc  = (const float*)d_in[13];
  const float* p1_bc  = (const float*)d_in[14];
  const float* p1_ac  = (const float*)d_in[15];
  const float* p1_Wl  = (const float*)d_in[16];
  const int* rec_C    = (const int*)d_in[17];
  const int* bins1    = (const int*)d_in[18];
  const int* child_idx= (const int*)d_in[19];
  const int* child_C  = (const int*)d_in[20];
  const int* bins0    = (const int*)d_in[21];

  const int N = in_sizes[0] / 64;   // 200000
  const int M = in_sizes[19];       // 400000

  // ---- workspace carve-up (~296 MB total) ----
  char* ws = (char*)d_ws;
  size_t off = 0;
  auto alloc = [&](size_t bytes) -> char* {
    char* p = ws + off;
    off += (bytes + 255) & ~(size_t)255;
    return p;
  };
  const int HRB = 19, HCB = 20;
  const uint32_t HR = 1u << HRB, HC = 1u << HCB;
  uint32_t* rkeys = (uint32_t*)alloc((size_t)HR * 4);
  int*      rvals = (int*)alloc((size_t)HR * 4);
  uint32_t* ckeys = (uint32_t*)alloc((size_t)HC * 4);
  int*      cvals = (int*)alloc((size_t)HC * 4);
  int* nbrR = (int*)alloc((size_t)N * 27 * 4);
  int* nbrC = (int*)alloc((size_t)M * 27 * 4);
  short* wpack = (short*)alloc((size_t)4 * 110592 * 2);  // 4 convs
  short* decwp = (short*)alloc((size_t)3 * 4 * 64 * 8 * 2);
  short* p0wp  = (short*)alloc((size_t)2 * 32 * 64 * 8 * 2);
  short* p1wp  = (short*)alloc((size_t)2 * 16 * 64 * 8 * 2);
  short* bufA = (short*)alloc((size_t)N * 64 * 2);  // hq, later pq
  short* bufB = (short*)alloc((size_t)N * 64 * 2);  // r1q, later qq
  float* h32  = (float*)alloc((size_t)N * 64 * 4);
  short* tq   = (short*)alloc((size_t)M * 64 * 2);
  short* uq   = (short*)alloc((size_t)M * 64 * 2);
  int* lists  = (int*)alloc((size_t)8 * M * 4);
  int* bcnt   = (int*)alloc(256);

  float* outRec  = (float*)d_out;
  float* outPred = outRec + (size_t)N * 64;
  float* outOct  = outPred + (size_t)M * 255;

  dim3 B(256);

  // setup
  k_fill_u32<<<(HR + 255) / 256, B, 0, stream>>>(rkeys, HR, EMPTY_KEY);
  k_fill_u32<<<(HC + 255) / 256, B, 0, stream>>>(ckeys, HC, EMPTY_KEY);
  k_fill_u32<<<1, B, 0, stream>>>((uint32_t*)bcnt, 8, 0u);
  k_hash_insert<<<(N + 255) / 256, B, 0, stream>>>(rec_C, N, rkeys, rvals, HR - 1);
  k_hash_insert<<<(M + 255) / 256, B, 0, stream>>>(child_C, M, ckeys, cvals, HC - 1);
  k_build_nbr<<<(N * 27 + 255) / 256, B, 0, stream>>>(rec_C, N, 2, rkeys, rvals, HR - 1, nbrR);
  k_build_nbr<<<(M * 27 + 255) / 256, B, 0, stream>>>(child_C, M, 1, ckeys, cvals, HC - 1, nbrC);
  k_pack_conv<<<54, B, 0, stream>>>(res_W1, wpack);
  k_pack_conv<<<54, B, 0, stream>>>(res_W2, wpack + 110592);
  k_pack_conv<<<54, B, 0, stream>>>(p0_Wc, wpack + 221184);
  k_pack_conv<<<54, B, 0, stream>>>(p1_Wc, wpack + 331776);
  k_pack_dense<<<3, B, 0, stream>>>(dec_W, decwp, 72, 64, 3, 4);
  k_pack_dense<<<16, B, 0, stream>>>(p0_Wl, p0wp, 64, 512, 2, 32);
  k_pack_dense<<<8, B, 0, stream>>>(p1_Wl, p1wp, 64, 255, 2, 16);
  k_bucket<<<(M + 255) / 256, B, 0, stream>>>(child_idx, M, lists, bcnt);

  // compute
  k_dec<<<N / 64, B, 0, stream>>>(rec_F, bins1, decwp, dec_b, dec_a, h32, bufA);
  k_conv<0><<<N / 64, B, 0, stream>>>(bufA, nbrR, wpack, res_b1, res_a1,
                                      nullptr, nullptr, bufB);
  k_conv<1><<<N / 64, B, 0, stream>>>(bufB, nbrR, wpack + 110592, res_b2, nullptr,
                                      h32, outRec, bufA);
  k_conv<0><<<N / 64, B, 0, stream>>>(bufA, nbrR, wpack + 221184, p0_bc, p0_ac,
                                      nullptr, nullptr, bufB);
  k_p0<<<dim3(M / 64, 8), B, 0, stream>>>(bufB, child_idx, lists, bcnt, p0wp, tq, M);
  k_conv<0><<<M / 64, B, 0, stream>>>(tq, nbrC, wpack + 331776, p1_bc, p1_ac,
                                      nullptr, nullptr, uq);
  k_p1<<<M / 64, B, 0, stream>>>(uq, p1wp, outPred);
  k_oct<<<(M + 255) / 256, B, 0, stream>>>(bins0, outOct, M);
}

// Round 2
// 1095.056 us; speedup vs baseline: 2.2495x; 2.2495x over previous
//
#include <hip/hip_runtime.h>
#include <stdint.h>

// ---------------------------------------------------------------------------
// OneScaleMultiStepPredictor — MFMA bf16 implementation.
//
// Pipeline (C=64 everywhere):
//   h  = prelu(requant([rec_F | bins1]) @ dec_W + dec_b, dec_a)          [N,64]
//   r1 = requant(prelu(conv27(rec, requant(h), W1) + b1, a1))            [N,64]
//   r2 = conv27(rec, r1, W2) + b2 ; rec_out = h + r2  -> d_out[0:N*64]
//   pq = requant(rec_out)
//   qq = requant(prelu(conv27(rec, pq, p0_Wc) + p0_bc, p0_ac))
//   tq = requant( qq[parent(m)] @ p0_Wl[:, bit(m)*64 : +64] )            [M,64]
//   uq = requant(prelu(conv27(child, tq, p1_Wc) + p1_bc, p1_ac))
//   pred = uq @ p1_Wl  -> d_out[N*64 : +M*255]
//   oct  = sum(bins0<<k)-1 -> d_out[N*64+M*255 : +M]
//
// R1 change: k_bucket used 400k atomicAdds on 8 global counters -> 1347 us
// (55% of total, pure contention). Replaced with per-block LDS histogram +
// 8 global atomics per block (12.5k total) + positioned writes.
// ---------------------------------------------------------------------------

typedef short bf16x8 __attribute__((ext_vector_type(8)));
typedef float f32x4 __attribute__((ext_vector_type(4)));

#define EMPTY_KEY 0xFFFFFFFFu

__device__ __forceinline__ float rq(float x) {
  x *= (1.0f / 256.0f);
  return fminf(fmaxf(x, -128.0f), 127.0f);
}

__device__ __forceinline__ short f2b(float f) {  // fp32 -> bf16 (RNE)
  union { float f; uint32_t u; } v; v.f = f;
  uint32_t u = v.u;
  uint32_t r = (u + 0x7FFFu + ((u >> 16) & 1u)) >> 16;
  return (short)r;
}

__device__ __forceinline__ uint32_t hkey(int x, int y, int z) {
  // coords in [-2, 512]; +8 -> [6,520] < 1024 -> injective 30-bit key
  return ((uint32_t)(x + 8) << 20) | ((uint32_t)(y + 8) << 10) | (uint32_t)(z + 8);
}
__device__ __forceinline__ uint32_t hfun(uint32_t key, uint32_t mask) {
  return (key * 2654435761u) & mask;
}

// ------------------------------ setup kernels ------------------------------

__global__ void k_fill_u32(uint32_t* p, int n, uint32_t v) {
  int i = blockIdx.x * 256 + threadIdx.x;
  if (i < n) p[i] = v;
}

__global__ void k_hash_insert(const int* __restrict__ coords, int n,
                              uint32_t* __restrict__ keys, int* __restrict__ vals,
                              uint32_t mask) {
  int i = blockIdx.x * 256 + threadIdx.x;
  if (i >= n) return;
  uint32_t key = hkey(coords[i * 3], coords[i * 3 + 1], coords[i * 3 + 2]);
  uint32_t s = hfun(key, mask);
  while (true) {
    uint32_t old = atomicCAS(&keys[s], EMPTY_KEY, key);
    if (old == EMPTY_KEY) { vals[s] = i; return; }   // coords are unique
    s = (s + 1) & mask;
  }
}

__global__ void k_build_nbr(const int* __restrict__ coords, int n, int stride,
                            const uint32_t* __restrict__ keys,
                            const int* __restrict__ vals, uint32_t mask,
                            int* __restrict__ nbr) {
  int t = blockIdx.x * 256 + threadIdx.x;
  if (t >= n * 27) return;
  int i = t / 27, k = t % 27;
  int dx = k / 9 - 1, dy = (k / 3) % 3 - 1, dz = k % 3 - 1;
  int x = coords[i * 3] + dx * stride;
  int y = coords[i * 3 + 1] + dy * stride;
  int z = coords[i * 3 + 2] + dz * stride;
  uint32_t key = hkey(x, y, z);
  uint32_t s = hfun(key, mask);
  int res = -1;
  while (true) {
    uint32_t kk = keys[s];
    if (kk == key) { res = vals[s]; break; }
    if (kk == EMPTY_KEY) break;
    s = (s + 1) & mask;
  }
  nbr[t] = res;
}

// Pack conv weight W[27][64][64] (fp32) -> [k][t][c][lane][8] bf16 fragments.
__global__ void k_pack_conv(const float* __restrict__ W, short* __restrict__ dst) {
  int gid = blockIdx.x * 256 + threadIdx.x;
  if (gid >= 27 * 2 * 4 * 64) return;
  int lane = gid & 63;
  int c = (gid >> 6) & 3;
  int t = (gid >> 8) & 1;
  int k = gid >> 9;
  int n = c * 16 + (lane & 15);
  int g = lane >> 4;
  bf16x8 v;
#pragma unroll
  for (int e = 0; e < 8; e++) {
    int kk = t * 32 + g * 8 + e;
    v[e] = f2b(W[(k * 64 + kk) * 64 + n]);
  }
  *(bf16x8*)(dst + gid * 8) = v;
}

// Pack dense weight [K][Ncols] fp32 -> [t][c][lane][8] bf16 (zero-padded).
__global__ void k_pack_dense(const float* __restrict__ W, short* __restrict__ dst,
                             int K, int Ncols, int KT, int CT) {
  int gid = blockIdx.x * 256 + threadIdx.x;
  if (gid >= KT * CT * 64) return;
  int lane = gid & 63;
  int c = (gid >> 6) % CT;
  int t = gid / (64 * CT);
  int n = c * 16 + (lane & 15);
  int g = lane >> 4;
  bf16x8 v;
#pragma unroll
  for (int e = 0; e < 8; e++) {
    int kk = t * 32 + g * 8 + e;
    float val = (kk < K && n < Ncols) ? W[kk * Ncols + n] : 0.0f;
    v[e] = f2b(val);
  }
  *(bf16x8*)(dst + gid * 8) = v;
}

// Hierarchical bucketing: LDS histogram per block, 8 global atomics per block.
__global__ void __launch_bounds__(256)
k_bucket(const int* __restrict__ child_idx, int M,
         int* __restrict__ lists, int* __restrict__ cnt) {
  __shared__ int lcnt[8];
  __shared__ int lbase[8];
  int tid = threadIdx.x;
  if (tid < 8) lcnt[tid] = 0;
  __syncthreads();
  int m = blockIdx.x * 256 + tid;
  int b = 0, lp = 0;
  if (m < M) {
    b = child_idx[m] & 7;
    lp = atomicAdd(&lcnt[b], 1);
  }
  __syncthreads();
  if (tid < 8) lbase[tid] = atomicAdd(&cnt[tid], lcnt[tid]);
  __syncthreads();
  if (m < M) lists[(size_t)b * M + lbase[b] + lp] = m;
}

// ------------------------------ compute kernels ----------------------------

// dec: h = prelu(requant([rec_F | bins1]) @ dec_W + b, a); h32 + requant bf16
__global__ void __launch_bounds__(256)
k_dec(const float* __restrict__ recF, const int* __restrict__ bits,
      const short* __restrict__ wp, const float* __restrict__ bias,
      const float* __restrict__ alpha, float* __restrict__ h32,
      short* __restrict__ hq) {
  int tid = threadIdx.x, wid = tid >> 6, lane = tid & 63;
  int rowbase = blockIdx.x * 64 + wid * 16;
  int lrow = rowbase + (lane & 15);
  int g = lane >> 4;
  f32x4 acc[4] = {};
#pragma unroll
  for (int t = 0; t < 3; t++) {
    bf16x8 a = {0, 0, 0, 0, 0, 0, 0, 0};
    if (t < 2) {
      const float* src = recF + (size_t)lrow * 64 + t * 32 + g * 8;
#pragma unroll
      for (int e = 0; e < 8; e++) a[e] = f2b(rq(src[e]));
    } else if (g == 0) {
      const int* bp = bits + (size_t)lrow * 8;
#pragma unroll
      for (int e = 0; e < 8; e++) a[e] = f2b((float)bp[e]);  // requant(bit*256)=bit
    }
#pragma unroll
    for (int c = 0; c < 4; c++) {
      bf16x8 b = *(const bf16x8*)(wp + ((t * 4 + c) * 64 + lane) * 8);
      acc[c] = __builtin_amdgcn_mfma_f32_16x16x32_bf16(a, b, acc[c], 0, 0, 0);
    }
  }
#pragma unroll
  for (int c = 0; c < 4; c++) {
    int col = c * 16 + (lane & 15);
    float bi = bias[col], al = alpha[col];
#pragma unroll
    for (int r = 0; r < 4; r++) {
      int row = rowbase + g * 4 + r;
      float v = acc[c][r] + bi;
      v = v >= 0.0f ? v : al * v;
      h32[(size_t)row * 64 + col] = v;
      hq[(size_t)row * 64 + col] = f2b(rq(v));
    }
  }
}

// 27-point gather conv. MODE 0: outq = requant(prelu(acc+b, a)).
// MODE 1: out32 = resid + acc + b (written to d_out); outq = requant(out32).
template <int MODE>
__global__ void __launch_bounds__(256)
k_conv(const short* __restrict__ fin, const int* __restrict__ nbr,
       const short* __restrict__ wp, const float* __restrict__ bias,
       const float* __restrict__ alpha, const float* __restrict__ resid,
       float* __restrict__ out32, short* __restrict__ outq) {
  int tid = threadIdx.x, wid = tid >> 6, lane = tid & 63;
  int rowbase = blockIdx.x * 64 + wid * 16;
  int lrow = rowbase + (lane & 15);
  int g = lane >> 4;
  f32x4 acc[4] = {};
  for (int k = 0; k < 27; k++) {
    int nb = nbr[(size_t)lrow * 27 + k];
    bf16x8 a0 = {0, 0, 0, 0, 0, 0, 0, 0};
    bf16x8 a1 = {0, 0, 0, 0, 0, 0, 0, 0};
    if (nb >= 0) {
      const short* fp = fin + (size_t)nb * 64 + g * 8;
      a0 = *(const bf16x8*)fp;
      a1 = *(const bf16x8*)(fp + 32);
    }
    const short* wk = wp + k * 4096;
#pragma unroll
    for (int c = 0; c < 4; c++) {
      bf16x8 b0 = *(const bf16x8*)(wk + (c * 64 + lane) * 8);
      acc[c] = __builtin_amdgcn_mfma_f32_16x16x32_bf16(a0, b0, acc[c], 0, 0, 0);
    }
#pragma unroll
    for (int c = 0; c < 4; c++) {
      bf16x8 b1 = *(const bf16x8*)(wk + ((4 + c) * 64 + lane) * 8);
      acc[c] = __builtin_amdgcn_mfma_f32_16x16x32_bf16(a1, b1, acc[c], 0, 0, 0);
    }
  }
#pragma unroll
  for (int c = 0; c < 4; c++) {
    int col = c * 16 + (lane & 15);
    float bi = bias[col];
    float al = (MODE == 0) ? alpha[col] : 0.0f;
#pragma unroll
    for (int r = 0; r < 4; r++) {
      int row = rowbase + g * 4 + r;
      float v = acc[c][r] + bi;
      if (MODE == 0) {
        v = v >= 0.0f ? v : al * v;
        outq[(size_t)row * 64 + col] = f2b(rq(v));
      } else {
        v += resid[(size_t)row * 64 + col];
        out32[(size_t)row * 64 + col] = v;
        outq[(size_t)row * 64 + col] = f2b(rq(v));
      }
    }
  }
}

// Bucketed p0_Wl projection: tq[m] = requant(qq[parent(m)] @ p0_Wl[:, bit*64:+64])
__global__ void __launch_bounds__(256)
k_p0(const short* __restrict__ qq, const int* __restrict__ child_idx,
     const int* __restrict__ lists, const int* __restrict__ cnt,
     const short* __restrict__ wp, short* __restrict__ tq, int M) {
  int b = blockIdx.y;
  int cb = cnt[b];
  int start = blockIdx.x * 64;
  if (start >= cb) return;
  int tid = threadIdx.x, wid = tid >> 6, lane = tid & 63, g = lane >> 4;
  int posA = start + wid * 16 + (lane & 15);
  int parent = -1;
  if (posA < cb) parent = child_idx[lists[(size_t)b * M + posA]] >> 3;
  f32x4 acc[4] = {};
#pragma unroll
  for (int t = 0; t < 2; t++) {
    bf16x8 a = {0, 0, 0, 0, 0, 0, 0, 0};
    if (parent >= 0) a = *(const bf16x8*)(qq + (size_t)parent * 64 + t * 32 + g * 8);
#pragma unroll
    for (int c = 0; c < 4; c++) {
      bf16x8 bb = *(const bf16x8*)(wp + (((size_t)t * 32 + b * 4 + c) * 64 + lane) * 8);
      acc[c] = __builtin_amdgcn_mfma_f32_16x16x32_bf16(a, bb, acc[c], 0, 0, 0);
    }
  }
#pragma unroll
  for (int r = 0; r < 4; r++) {
    int posD = start + wid * 16 + g * 4 + r;
    if (posD < cb) {
      int m = lists[(size_t)b * M + posD];
#pragma unroll
      for (int c = 0; c < 4; c++) {
        int col = c * 16 + (lane & 15);
        tq[(size_t)m * 64 + col] = f2b(rq(acc[c][r]));
      }
    }
  }
}

// pred = uq @ p1_Wl  (255 cols, padded to 256)
__global__ void __launch_bounds__(256)
k_p1(const short* __restrict__ uq, const short* __restrict__ wp,
     float* __restrict__ out) {
  int tid = threadIdx.x, wid = tid >> 6, lane = tid & 63, g = lane >> 4;
  int rowbase = blockIdx.x * 64 + wid * 16;
  int lrow = rowbase + (lane & 15);
  f32x4 acc[16] = {};
#pragma unroll
  for (int t = 0; t < 2; t++) {
    bf16x8 a = *(const bf16x8*)(uq + (size_t)lrow * 64 + t * 32 + g * 8);
#pragma unroll
    for (int c = 0; c < 16; c++) {
      bf16x8 bb = *(const bf16x8*)(wp + ((t * 16 + c) * 64 + lane) * 8);
      acc[c] = __builtin_amdgcn_mfma_f32_16x16x32_bf16(a, bb, acc[c], 0, 0, 0);
    }
  }
#pragma unroll
  for (int c = 0; c < 16; c++) {
    int col = c * 16 + (lane & 15);
    if (col < 255) {
#pragma unroll
      for (int r = 0; r < 4; r++) {
        int row = rowbase + g * 4 + r;
        out[(size_t)row * 255 + col] = acc[c][r];
      }
    }
  }
}

__global__ void k_oct(const int* __restrict__ bins0, float* __restrict__ out, int M) {
  int m = blockIdx.x * 256 + threadIdx.x;
  if (m >= M) return;
  int s = 0;
#pragma unroll
  for (int e = 0; e < 8; e++) s += bins0[(size_t)m * 8 + e] << e;
  out[m] = (float)(s - 1);
}

// ------------------------------ host launcher ------------------------------

extern "C" void kernel_launch(void* const* d_in, const int* in_sizes, int n_in,
                              void* d_out, int out_size, void* d_ws, size_t ws_size,
                              hipStream_t stream) {
  const float* rec_F  = (const float*)d_in[0];
  const float* dec_W  = (const float*)d_in[1];
  const float* dec_b  = (const float*)d_in[2];
  const float* dec_a  = (const float*)d_in[3];
  const float* res_W1 = (const float*)d_in[4];
  const float* res_b1 = (const float*)d_in[5];
  const float* res_a1 = (const float*)d_in[6];
  const float* res_W2 = (const float*)d_in[7];
  const float* res_b2 = (const float*)d_in[8];
  const float* p0_Wc  = (const float*)d_in[9];
  const float* p0_bc  = (const float*)d_in[10];
  const float* p0_ac  = (const float*)d_in[11];
  const float* p0_Wl  = (const float*)d_in[12];
  const float* p1_Wc  = (const float*)d_in[13];
  const float* p1_bc  = (const float*)d_in[14];
  const float* p1_ac  = (const float*)d_in[15];
  const float* p1_Wl  = (const float*)d_in[16];
  const int* rec_C    = (const int*)d_in[17];
  const int* bins1    = (const int*)d_in[18];
  const int* child_idx= (const int*)d_in[19];
  const int* child_C  = (const int*)d_in[20];
  const int* bins0    = (const int*)d_in[21];

  const int N = in_sizes[0] / 64;   // 200000
  const int M = in_sizes[19];       // 400000

  // ---- workspace carve-up (~296 MB total) ----
  char* ws = (char*)d_ws;
  size_t off = 0;
  auto alloc = [&](size_t bytes) -> char* {
    char* p = ws + off;
    off += (bytes + 255) & ~(size_t)255;
    return p;
  };
  const int HRB = 19, HCB = 20;
  const uint32_t HR = 1u << HRB, HC = 1u << HCB;
  uint32_t* rkeys = (uint32_t*)alloc((size_t)HR * 4);
  int*      rvals = (int*)alloc((size_t)HR * 4);
  uint32_t* ckeys = (uint32_t*)alloc((size_t)HC * 4);
  int*      cvals = (int*)alloc((size_t)HC * 4);
  int* nbrR = (int*)alloc((size_t)N * 27 * 4);
  int* nbrC = (int*)alloc((size_t)M * 27 * 4);
  short* wpack = (short*)alloc((size_t)4 * 110592 * 2);  // 4 convs
  short* decwp = (short*)alloc((size_t)3 * 4 * 64 * 8 * 2);
  short* p0wp  = (short*)alloc((size_t)2 * 32 * 64 * 8 * 2);
  short* p1wp  = (short*)alloc((size_t)2 * 16 * 64 * 8 * 2);
  short* bufA = (short*)alloc((size_t)N * 64 * 2);  // hq, later pq
  short* bufB = (short*)alloc((size_t)N * 64 * 2);  // r1q, later qq
  float* h32  = (float*)alloc((size_t)N * 64 * 4);
  short* tq   = (short*)alloc((size_t)M * 64 * 2);
  short* uq   = (short*)alloc((size_t)M * 64 * 2);
  int* lists  = (int*)alloc((size_t)8 * M * 4);
  int* bcnt   = (int*)alloc(256);

  float* outRec  = (float*)d_out;
  float* outPred = outRec + (size_t)N * 64;
  float* outOct  = outPred + (size_t)M * 255;

  dim3 B(256);

  // setup
  k_fill_u32<<<(HR + 255) / 256, B, 0, stream>>>(rkeys, HR, EMPTY_KEY);
  k_fill_u32<<<(HC + 255) / 256, B, 0, stream>>>(ckeys, HC, EMPTY_KEY);
  k_fill_u32<<<1, B, 0, stream>>>((uint32_t*)bcnt, 8, 0u);
  k_hash_insert<<<(N + 255) / 256, B, 0, stream>>>(rec_C, N, rkeys, rvals, HR - 1);
  k_hash_insert<<<(M + 255) / 256, B, 0, stream>>>(child_C, M, ckeys, cvals, HC - 1);
  k_build_nbr<<<(N * 27 + 255) / 256, B, 0, stream>>>(rec_C, N, 2, rkeys, rvals, HR - 1, nbrR);
  k_build_nbr<<<(M * 27 + 255) / 256, B, 0, stream>>>(child_C, M, 1, ckeys, cvals, HC - 1, nbrC);
  k_pack_conv<<<54, B, 0, stream>>>(res_W1, wpack);
  k_pack_conv<<<54, B, 0, stream>>>(res_W2, wpack + 110592);
  k_pack_conv<<<54, B, 0, stream>>>(p0_Wc, wpack + 221184);
  k_pack_conv<<<54, B, 0, stream>>>(p1_Wc, wpack + 331776);
  k_pack_dense<<<3, B, 0, stream>>>(dec_W, decwp, 72, 64, 3, 4);
  k_pack_dense<<<16, B, 0, stream>>>(p0_Wl, p0wp, 64, 512, 2, 32);
  k_pack_dense<<<8, B, 0, stream>>>(p1_Wl, p1wp, 64, 255, 2, 16);
  k_bucket<<<(M + 255) / 256, B, 0, stream>>>(child_idx, M, lists, bcnt);

  // compute
  k_dec<<<N / 64, B, 0, stream>>>(rec_F, bins1, decwp, dec_b, dec_a, h32, bufA);
  k_conv<0><<<N / 64, B, 0, stream>>>(bufA, nbrR, wpack, res_b1, res_a1,
                                      nullptr, nullptr, bufB);
  k_conv<1><<<N / 64, B, 0, stream>>>(bufB, nbrR, wpack + 110592, res_b2, nullptr,
                                      h32, outRec, bufA);
  k_conv<0><<<N / 64, B, 0, stream>>>(bufA, nbrR, wpack + 221184, p0_bc, p0_ac,
                                      nullptr, nullptr, bufB);
  k_p0<<<dim3(M / 64, 8), B, 0, stream>>>(bufB, child_idx, lists, bcnt, p0wp, tq, M);
  k_conv<0><<<M / 64, B, 0, stream>>>(tq, nbrC, wpack + 331776, p1_bc, p1_ac,
                                      nullptr, nullptr, uq);
  k_p1<<<M / 64, B, 0, stream>>>(uq, p1wp, outPred);
  k_oct<<<(M + 255) / 256, B, 0, stream>>>(bins0, outOct, M);
}

// Round 3
// 783.762 us; speedup vs baseline: 3.1430x; 1.3972x over previous
//
#include <hip/hip_runtime.h>
#include <stdint.h>

// ---------------------------------------------------------------------------
// OneScaleMultiStepPredictor — MFMA bf16 implementation.
//
// Pipeline (C=64 everywhere):
//   h  = prelu(requant([rec_F | bins1]) @ dec_W + dec_b, dec_a)          [N,64]
//   r1 = requant(prelu(conv27(rec, requant(h), W1) + b1, a1))            [N,64]
//   r2 = conv27(rec, r1, W2) + b2 ; rec_out = h + r2  -> d_out[0:N*64]
//   pq = requant(rec_out)
//   qq = requant(prelu(conv27(rec, pq, p0_Wc) + p0_bc, p0_ac))
//   tq = requant( qq[parent(m)] @ p0_Wl[:, bit(m)*64 : +64] )            [M,64]
//   uq = requant(prelu(conv27(child, tq, p1_Wc) + p1_bc, p1_ac))
//   pred = uq @ p1_Wl  -> d_out[N*64 : +M*255]
//   oct  = sum(bins0<<k)-1 -> d_out[N*64+M*255 : +M]
//
// R2 change: convs were latency-bound (MfmaUtil 13.5%, HBM 4.8%). Rec graph
// is 1.2% occupied -> ~5.5 of 27 offsets active per 16-row tile; child graph
// ~19 of 27. Now: nbr stride padded to 28, whole neighbor list prefetched as
// 7x int4, and per-offset wave-uniform __any() skip of gather+MFMA.
// ---------------------------------------------------------------------------

typedef short bf16x8 __attribute__((ext_vector_type(8)));
typedef float f32x4 __attribute__((ext_vector_type(4)));

#define EMPTY_KEY 0xFFFFFFFFu

__device__ __forceinline__ float rq(float x) {
  x *= (1.0f / 256.0f);
  return fminf(fmaxf(x, -128.0f), 127.0f);
}

__device__ __forceinline__ short f2b(float f) {  // fp32 -> bf16 (RNE)
  union { float f; uint32_t u; } v; v.f = f;
  uint32_t u = v.u;
  uint32_t r = (u + 0x7FFFu + ((u >> 16) & 1u)) >> 16;
  return (short)r;
}

__device__ __forceinline__ uint32_t hkey(int x, int y, int z) {
  // coords in [-2, 512]; +8 -> [6,520] < 1024 -> injective 30-bit key
  return ((uint32_t)(x + 8) << 20) | ((uint32_t)(y + 8) << 10) | (uint32_t)(z + 8);
}
__device__ __forceinline__ uint32_t hfun(uint32_t key, uint32_t mask) {
  return (key * 2654435761u) & mask;
}

// ------------------------------ setup kernels ------------------------------

__global__ void k_fill_u32(uint32_t* p, int n, uint32_t v) {
  int i = blockIdx.x * 256 + threadIdx.x;
  if (i < n) p[i] = v;
}

__global__ void k_hash_insert(const int* __restrict__ coords, int n,
                              uint32_t* __restrict__ keys, int* __restrict__ vals,
                              uint32_t mask) {
  int i = blockIdx.x * 256 + threadIdx.x;
  if (i >= n) return;
  uint32_t key = hkey(coords[i * 3], coords[i * 3 + 1], coords[i * 3 + 2]);
  uint32_t s = hfun(key, mask);
  while (true) {
    uint32_t old = atomicCAS(&keys[s], EMPTY_KEY, key);
    if (old == EMPTY_KEY) { vals[s] = i; return; }   // coords are unique
    s = (s + 1) & mask;
  }
}

// nbr has row stride 28 (int4-aligned); entry 27 is padding (never used).
__global__ void k_build_nbr(const int* __restrict__ coords, int n, int stride,
                            const uint32_t* __restrict__ keys,
                            const int* __restrict__ vals, uint32_t mask,
                            int* __restrict__ nbr) {
  int t = blockIdx.x * 256 + threadIdx.x;
  if (t >= n * 27) return;
  int i = t / 27, k = t % 27;
  int dx = k / 9 - 1, dy = (k / 3) % 3 - 1, dz = k % 3 - 1;
  int x = coords[i * 3] + dx * stride;
  int y = coords[i * 3 + 1] + dy * stride;
  int z = coords[i * 3 + 2] + dz * stride;
  uint32_t key = hkey(x, y, z);
  uint32_t s = hfun(key, mask);
  int res = -1;
  while (true) {
    uint32_t kk = keys[s];
    if (kk == key) { res = vals[s]; break; }
    if (kk == EMPTY_KEY) break;
    s = (s + 1) & mask;
  }
  nbr[(size_t)i * 28 + k] = res;
}

// Pack conv weight W[27][64][64] (fp32) -> [k][t][c][lane][8] bf16 fragments.
__global__ void k_pack_conv(const float* __restrict__ W, short* __restrict__ dst) {
  int gid = blockIdx.x * 256 + threadIdx.x;
  if (gid >= 27 * 2 * 4 * 64) return;
  int lane = gid & 63;
  int c = (gid >> 6) & 3;
  int t = (gid >> 8) & 1;
  int k = gid >> 9;
  int n = c * 16 + (lane & 15);
  int g = lane >> 4;
  bf16x8 v;
#pragma unroll
  for (int e = 0; e < 8; e++) {
    int kk = t * 32 + g * 8 + e;
    v[e] = f2b(W[(k * 64 + kk) * 64 + n]);
  }
  *(bf16x8*)(dst + gid * 8) = v;
}

// Pack dense weight [K][Ncols] fp32 -> [t][c][lane][8] bf16 (zero-padded).
__global__ void k_pack_dense(const float* __restrict__ W, short* __restrict__ dst,
                             int K, int Ncols, int KT, int CT) {
  int gid = blockIdx.x * 256 + threadIdx.x;
  if (gid >= KT * CT * 64) return;
  int lane = gid & 63;
  int c = (gid >> 6) % CT;
  int t = gid / (64 * CT);
  int n = c * 16 + (lane & 15);
  int g = lane >> 4;
  bf16x8 v;
#pragma unroll
  for (int e = 0; e < 8; e++) {
    int kk = t * 32 + g * 8 + e;
    float val = (kk < K && n < Ncols) ? W[kk * Ncols + n] : 0.0f;
    v[e] = f2b(val);
  }
  *(bf16x8*)(dst + gid * 8) = v;
}

// Hierarchical bucketing: LDS histogram per block, 8 global atomics per block.
__global__ void __launch_bounds__(256)
k_bucket(const int* __restrict__ child_idx, int M,
         int* __restrict__ lists, int* __restrict__ cnt) {
  __shared__ int lcnt[8];
  __shared__ int lbase[8];
  int tid = threadIdx.x;
  if (tid < 8) lcnt[tid] = 0;
  __syncthreads();
  int m = blockIdx.x * 256 + tid;
  int b = 0, lp = 0;
  if (m < M) {
    b = child_idx[m] & 7;
    lp = atomicAdd(&lcnt[b], 1);
  }
  __syncthreads();
  if (tid < 8) lbase[tid] = atomicAdd(&cnt[tid], lcnt[tid]);
  __syncthreads();
  if (m < M) lists[(size_t)b * M + lbase[b] + lp] = m;
}

// ------------------------------ compute kernels ----------------------------

// dec: h = prelu(requant([rec_F | bins1]) @ dec_W + b, a); h32 + requant bf16
__global__ void __launch_bounds__(256)
k_dec(const float* __restrict__ recF, const int* __restrict__ bits,
      const short* __restrict__ wp, const float* __restrict__ bias,
      const float* __restrict__ alpha, float* __restrict__ h32,
      short* __restrict__ hq) {
  int tid = threadIdx.x, wid = tid >> 6, lane = tid & 63;
  int rowbase = blockIdx.x * 64 + wid * 16;
  int lrow = rowbase + (lane & 15);
  int g = lane >> 4;
  f32x4 acc[4] = {};
#pragma unroll
  for (int t = 0; t < 3; t++) {
    bf16x8 a = {0, 0, 0, 0, 0, 0, 0, 0};
    if (t < 2) {
      const float* src = recF + (size_t)lrow * 64 + t * 32 + g * 8;
#pragma unroll
      for (int e = 0; e < 8; e++) a[e] = f2b(rq(src[e]));
    } else if (g == 0) {
      const int* bp = bits + (size_t)lrow * 8;
#pragma unroll
      for (int e = 0; e < 8; e++) a[e] = f2b((float)bp[e]);  // requant(bit*256)=bit
    }
#pragma unroll
    for (int c = 0; c < 4; c++) {
      bf16x8 b = *(const bf16x8*)(wp + ((t * 4 + c) * 64 + lane) * 8);
      acc[c] = __builtin_amdgcn_mfma_f32_16x16x32_bf16(a, b, acc[c], 0, 0, 0);
    }
  }
#pragma unroll
  for (int c = 0; c < 4; c++) {
    int col = c * 16 + (lane & 15);
    float bi = bias[col], al = alpha[col];
#pragma unroll
    for (int r = 0; r < 4; r++) {
      int row = rowbase + g * 4 + r;
      float v = acc[c][r] + bi;
      v = v >= 0.0f ? v : al * v;
      h32[(size_t)row * 64 + col] = v;
      hq[(size_t)row * 64 + col] = f2b(rq(v));
    }
  }
}

// 27-point gather conv with per-offset wave-uniform skip.
// MODE 0: outq = requant(prelu(acc+b, a)).
// MODE 1: out32 = resid + acc + b (written to d_out); outq = requant(out32).
template <int MODE>
__global__ void __launch_bounds__(256)
k_conv(const short* __restrict__ fin, const int* __restrict__ nbr,
       const short* __restrict__ wp, const float* __restrict__ bias,
       const float* __restrict__ alpha, const float* __restrict__ resid,
       float* __restrict__ out32, short* __restrict__ outq) {
  int tid = threadIdx.x, wid = tid >> 6, lane = tid & 63;
  int rowbase = blockIdx.x * 64 + wid * 16;
  int lrow = rowbase + (lane & 15);
  int g = lane >> 4;

  // Prefetch the full neighbor list for this lane's row: 7 independent int4
  // loads (stride 28, 16B-aligned). All-static indexing -> stays in VGPRs.
  int4 nv[7];
#pragma unroll
  for (int j = 0; j < 7; j++)
    nv[j] = *(const int4*)(nbr + (size_t)lrow * 28 + j * 4);
  int nbk[28];
#pragma unroll
  for (int j = 0; j < 7; j++) {
    nbk[j * 4 + 0] = nv[j].x;
    nbk[j * 4 + 1] = nv[j].y;
    nbk[j * 4 + 2] = nv[j].z;
    nbk[j * 4 + 3] = nv[j].w;
  }

  f32x4 acc[4] = {};
#pragma unroll
  for (int k = 0; k < 27; k++) {
    if (__any(nbk[k] >= 0)) {   // wave-uniform skip: no row in tile hits k
      int nb = nbk[k];
      bf16x8 a0 = {0, 0, 0, 0, 0, 0, 0, 0};
      bf16x8 a1 = {0, 0, 0, 0, 0, 0, 0, 0};
      if (nb >= 0) {
        const short* fp = fin + (size_t)nb * 64 + g * 8;
        a0 = *(const bf16x8*)fp;
        a1 = *(const bf16x8*)(fp + 32);
      }
      const short* wk = wp + k * 4096;
#pragma unroll
      for (int c = 0; c < 4; c++) {
        bf16x8 b0 = *(const bf16x8*)(wk + (c * 64 + lane) * 8);
        acc[c] = __builtin_amdgcn_mfma_f32_16x16x32_bf16(a0, b0, acc[c], 0, 0, 0);
      }
#pragma unroll
      for (int c = 0; c < 4; c++) {
        bf16x8 b1 = *(const bf16x8*)(wk + ((4 + c) * 64 + lane) * 8);
        acc[c] = __builtin_amdgcn_mfma_f32_16x16x32_bf16(a1, b1, acc[c], 0, 0, 0);
      }
    }
  }
#pragma unroll
  for (int c = 0; c < 4; c++) {
    int col = c * 16 + (lane & 15);
    float bi = bias[col];
    float al = (MODE == 0) ? alpha[col] : 0.0f;
#pragma unroll
    for (int r = 0; r < 4; r++) {
      int row = rowbase + g * 4 + r;
      float v = acc[c][r] + bi;
      if (MODE == 0) {
        v = v >= 0.0f ? v : al * v;
        outq[(size_t)row * 64 + col] = f2b(rq(v));
      } else {
        v += resid[(size_t)row * 64 + col];
        out32[(size_t)row * 64 + col] = v;
        outq[(size_t)row * 64 + col] = f2b(rq(v));
      }
    }
  }
}

// Bucketed p0_Wl projection: tq[m] = requant(qq[parent(m)] @ p0_Wl[:, bit*64:+64])
__global__ void __launch_bounds__(256)
k_p0(const short* __restrict__ qq, const int* __restrict__ child_idx,
     const int* __restrict__ lists, const int* __restrict__ cnt,
     const short* __restrict__ wp, short* __restrict__ tq, int M) {
  int b = blockIdx.y;
  int cb = cnt[b];
  int start = blockIdx.x * 64;
  if (start >= cb) return;
  int tid = threadIdx.x, wid = tid >> 6, lane = tid & 63, g = lane >> 4;
  int posA = start + wid * 16 + (lane & 15);
  int parent = -1;
  if (posA < cb) parent = child_idx[lists[(size_t)b * M + posA]] >> 3;
  f32x4 acc[4] = {};
#pragma unroll
  for (int t = 0; t < 2; t++) {
    bf16x8 a = {0, 0, 0, 0, 0, 0, 0, 0};
    if (parent >= 0) a = *(const bf16x8*)(qq + (size_t)parent * 64 + t * 32 + g * 8);
#pragma unroll
    for (int c = 0; c < 4; c++) {
      bf16x8 bb = *(const bf16x8*)(wp + (((size_t)t * 32 + b * 4 + c) * 64 + lane) * 8);
      acc[c] = __builtin_amdgcn_mfma_f32_16x16x32_bf16(a, bb, acc[c], 0, 0, 0);
    }
  }
#pragma unroll
  for (int r = 0; r < 4; r++) {
    int posD = start + wid * 16 + g * 4 + r;
    if (posD < cb) {
      int m = lists[(size_t)b * M + posD];
#pragma unroll
      for (int c = 0; c < 4; c++) {
        int col = c * 16 + (lane & 15);
        tq[(size_t)m * 64 + col] = f2b(rq(acc[c][r]));
      }
    }
  }
}

// pred = uq @ p1_Wl  (255 cols, padded to 256)
__global__ void __launch_bounds__(256)
k_p1(const short* __restrict__ uq, const short* __restrict__ wp,
     float* __restrict__ out) {
  int tid = threadIdx.x, wid = tid >> 6, lane = tid & 63, g = lane >> 4;
  int rowbase = blockIdx.x * 64 + wid * 16;
  int lrow = rowbase + (lane & 15);
  f32x4 acc[16] = {};
#pragma unroll
  for (int t = 0; t < 2; t++) {
    bf16x8 a = *(const bf16x8*)(uq + (size_t)lrow * 64 + t * 32 + g * 8);
#pragma unroll
    for (int c = 0; c < 16; c++) {
      bf16x8 bb = *(const bf16x8*)(wp + ((t * 16 + c) * 64 + lane) * 8);
      acc[c] = __builtin_amdgcn_mfma_f32_16x16x32_bf16(a, bb, acc[c], 0, 0, 0);
    }
  }
#pragma unroll
  for (int c = 0; c < 16; c++) {
    int col = c * 16 + (lane & 15);
    if (col < 255) {
#pragma unroll
      for (int r = 0; r < 4; r++) {
        int row = rowbase + g * 4 + r;
        out[(size_t)row * 255 + col] = acc[c][r];
      }
    }
  }
}

__global__ void k_oct(const int* __restrict__ bins0, float* __restrict__ out, int M) {
  int m = blockIdx.x * 256 + threadIdx.x;
  if (m >= M) return;
  int s = 0;
#pragma unroll
  for (int e = 0; e < 8; e++) s += bins0[(size_t)m * 8 + e] << e;
  out[m] = (float)(s - 1);
}

// ------------------------------ host launcher ------------------------------

extern "C" void kernel_launch(void* const* d_in, const int* in_sizes, int n_in,
                              void* d_out, int out_size, void* d_ws, size_t ws_size,
                              hipStream_t stream) {
  const float* rec_F  = (const float*)d_in[0];
  const float* dec_W  = (const float*)d_in[1];
  const float* dec_b  = (const float*)d_in[2];
  const float* dec_a  = (const float*)d_in[3];
  const float* res_W1 = (const float*)d_in[4];
  const float* res_b1 = (const float*)d_in[5];
  const float* res_a1 = (const float*)d_in[6];
  const float* res_W2 = (const float*)d_in[7];
  const float* res_b2 = (const float*)d_in[8];
  const float* p0_Wc  = (const float*)d_in[9];
  const float* p0_bc  = (const float*)d_in[10];
  const float* p0_ac  = (const float*)d_in[11];
  const float* p0_Wl  = (const float*)d_in[12];
  const float* p1_Wc  = (const float*)d_in[13];
  const float* p1_bc  = (const float*)d_in[14];
  const float* p1_ac  = (const float*)d_in[15];
  const float* p1_Wl  = (const float*)d_in[16];
  const int* rec_C    = (const int*)d_in[17];
  const int* bins1    = (const int*)d_in[18];
  const int* child_idx= (const int*)d_in[19];
  const int* child_C  = (const int*)d_in[20];
  const int* bins0    = (const int*)d_in[21];

  const int N = in_sizes[0] / 64;   // 200000
  const int M = in_sizes[19];       // 400000

  // ---- workspace carve-up (~300 MB total) ----
  char* ws = (char*)d_ws;
  size_t off = 0;
  auto alloc = [&](size_t bytes) -> char* {
    char* p = ws + off;
    off += (bytes + 255) & ~(size_t)255;
    return p;
  };
  const int HRB = 19, HCB = 20;
  const uint32_t HR = 1u << HRB, HC = 1u << HCB;
  uint32_t* rkeys = (uint32_t*)alloc((size_t)HR * 4);
  int*      rvals = (int*)alloc((size_t)HR * 4);
  uint32_t* ckeys = (uint32_t*)alloc((size_t)HC * 4);
  int*      cvals = (int*)alloc((size_t)HC * 4);
  int* nbrR = (int*)alloc((size_t)N * 28 * 4);
  int* nbrC = (int*)alloc((size_t)M * 28 * 4);
  short* wpack = (short*)alloc((size_t)4 * 110592 * 2);  // 4 convs
  short* decwp = (short*)alloc((size_t)3 * 4 * 64 * 8 * 2);
  short* p0wp  = (short*)alloc((size_t)2 * 32 * 64 * 8 * 2);
  short* p1wp  = (short*)alloc((size_t)2 * 16 * 64 * 8 * 2);
  short* bufA = (short*)alloc((size_t)N * 64 * 2);  // hq, later pq
  short* bufB = (short*)alloc((size_t)N * 64 * 2);  // r1q, later qq
  float* h32  = (float*)alloc((size_t)N * 64 * 4);
  short* tq   = (short*)alloc((size_t)M * 64 * 2);
  short* uq   = (short*)alloc((size_t)M * 64 * 2);
  int* lists  = (int*)alloc((size_t)8 * M * 4);
  int* bcnt   = (int*)alloc(256);

  float* outRec  = (float*)d_out;
  float* outPred = outRec + (size_t)N * 64;
  float* outOct  = outPred + (size_t)M * 255;

  dim3 B(256);

  // setup
  k_fill_u32<<<(HR + 255) / 256, B, 0, stream>>>(rkeys, HR, EMPTY_KEY);
  k_fill_u32<<<(HC + 255) / 256, B, 0, stream>>>(ckeys, HC, EMPTY_KEY);
  k_fill_u32<<<1, B, 0, stream>>>((uint32_t*)bcnt, 8, 0u);
  k_hash_insert<<<(N + 255) / 256, B, 0, stream>>>(rec_C, N, rkeys, rvals, HR - 1);
  k_hash_insert<<<(M + 255) / 256, B, 0, stream>>>(child_C, M, ckeys, cvals, HC - 1);
  k_build_nbr<<<(N * 27 + 255) / 256, B, 0, stream>>>(rec_C, N, 2, rkeys, rvals, HR - 1, nbrR);
  k_build_nbr<<<(M * 27 + 255) / 256, B, 0, stream>>>(child_C, M, 1, ckeys, cvals, HC - 1, nbrC);
  k_pack_conv<<<54, B, 0, stream>>>(res_W1, wpack);
  k_pack_conv<<<54, B, 0, stream>>>(res_W2, wpack + 110592);
  k_pack_conv<<<54, B, 0, stream>>>(p0_Wc, wpack + 221184);
  k_pack_conv<<<54, B, 0, stream>>>(p1_Wc, wpack + 331776);
  k_pack_dense<<<3, B, 0, stream>>>(dec_W, decwp, 72, 64, 3, 4);
  k_pack_dense<<<16, B, 0, stream>>>(p0_Wl, p0wp, 64, 512, 2, 32);
  k_pack_dense<<<8, B, 0, stream>>>(p1_Wl, p1wp, 64, 255, 2, 16);
  k_bucket<<<(M + 255) / 256, B, 0, stream>>>(child_idx, M, lists, bcnt);

  // compute
  k_dec<<<N / 64, B, 0, stream>>>(rec_F, bins1, decwp, dec_b, dec_a, h32, bufA);
  k_conv<0><<<N / 64, B, 0, stream>>>(bufA, nbrR, wpack, res_b1, res_a1,
                                      nullptr, nullptr, bufB);
  k_conv<1><<<N / 64, B, 0, stream>>>(bufB, nbrR, wpack + 110592, res_b2, nullptr,
                                      h32, outRec, bufA);
  k_conv<0><<<N / 64, B, 0, stream>>>(bufA, nbrR, wpack + 221184, p0_bc, p0_ac,
                                      nullptr, nullptr, bufB);
  k_p0<<<dim3(M / 64, 8), B, 0, stream>>>(bufB, child_idx, lists, bcnt, p0wp, tq, M);
  k_conv<0><<<M / 64, B, 0, stream>>>(tq, nbrC, wpack + 331776, p1_bc, p1_ac,
                                      nullptr, nullptr, uq);
  k_p1<<<M / 64, B, 0, stream>>>(uq, p1wp, outPred);
  k_oct<<<(M + 255) / 256, B, 0, stream>>>(bins0, outOct, M);
}